// Round 1
// baseline (849.942 us; speedup 1.0000x reference)
//
#include <hip/hip_runtime.h>

#define N_NODES 100000
#define N_EDGES 1600000
constexpr float BN_EPS = 1e-5f;

// ---------------- edge_index dtype detection (int32 vs int64) ----------------
// If the buffer is int64, every odd 32-bit word (high half) is 0 (values < 1e5).
// If int32, odd words are random src values (nonzero w.h.p.).
__global__ void detect_kernel(const int* __restrict__ ep, int* __restrict__ flag)
{
    __shared__ int cnt;
    if (threadIdx.x == 0) cnt = 0;
    __syncthreads();
    int nz = 0;
    for (int k = threadIdx.x; k < 1024; k += blockDim.x)
        if (ep[2 * k + 1] != 0) nz++;
    atomicAdd(&cnt, nz);
    __syncthreads();
    if (threadIdx.x == 0) *flag = (cnt == 0) ? 1 : 0;
}

// ---------------- degree histogram over dst ----------------
__global__ void hist_kernel(const int* __restrict__ ep, const int* __restrict__ flag,
                            int* __restrict__ cnt)
{
    bool i64 = (*flag != 0);
    int stride = gridDim.x * blockDim.x;
    for (int e = blockIdx.x * blockDim.x + threadIdx.x; e < N_EDGES; e += stride) {
        int d = i64 ? ep[2 * (N_EDGES + e)] : ep[N_EDGES + e];
        atomicAdd(&cnt[d], 1);
    }
}

// ---------------- exclusive scan (3 kernels), chunk = 1024/block ----------------
__global__ void scan1_kernel(const int* __restrict__ cnt, int* __restrict__ rowptr,
                             int* __restrict__ bsum)
{
    __shared__ int sh[256];
    int b = blockIdx.x, t = threadIdx.x;
    int base = b * 1024 + t * 4;
    int v[4];
    int tot = 0;
#pragma unroll
    for (int j = 0; j < 4; j++) {
        int idx = base + j;
        v[j] = (idx < N_NODES) ? cnt[idx] : 0;
        tot += v[j];
    }
    sh[t] = tot;
    __syncthreads();
    for (int off = 1; off < 256; off <<= 1) {
        int add = (t >= off) ? sh[t - off] : 0;
        __syncthreads();
        sh[t] += add;
        __syncthreads();
    }
    int p = sh[t] - tot; // exclusive offset of this thread within block
#pragma unroll
    for (int j = 0; j < 4; j++) {
        int idx = base + j;
        if (idx < N_NODES) rowptr[idx] = p;
        p += v[j];
    }
    if (t == 255) bsum[b] = sh[255];
}

__global__ void scan2_kernel(const int* __restrict__ bsum, int* __restrict__ bscan, int nb)
{
    __shared__ int sh[128];
    int t = threadIdx.x;
    int v = (t < nb) ? bsum[t] : 0;
    sh[t] = v;
    __syncthreads();
    for (int off = 1; off < 128; off <<= 1) {
        int add = (t >= off) ? sh[t - off] : 0;
        __syncthreads();
        sh[t] += add;
        __syncthreads();
    }
    if (t < nb) bscan[t] = sh[t] - v;
}

__global__ void scan3_kernel(int* __restrict__ rowptr, const int* __restrict__ bscan,
                             const int* __restrict__ cnt, int* __restrict__ nextp,
                             float* __restrict__ dinv)
{
    int b = blockIdx.x;
    int base = b * 1024 + threadIdx.x * 4;
    int add = bscan[b];
#pragma unroll
    for (int j = 0; j < 4; j++) {
        int i = base + j;
        if (i < N_NODES) {
            int r = rowptr[i] + add;
            rowptr[i] = r;
            nextp[i] = r;
            dinv[i] = rsqrtf((float)(cnt[i] + 1)); // +1 self-loop
        }
    }
    if (b == 0 && threadIdx.x == 0) rowptr[N_NODES] = N_EDGES;
}

// ---------------- CSR fill ----------------
__global__ void fill_kernel(const int* __restrict__ ep, const int* __restrict__ flag,
                            int* __restrict__ nextp, int* __restrict__ colidx)
{
    bool i64 = (*flag != 0);
    int stride = gridDim.x * blockDim.x;
    for (int e = blockIdx.x * blockDim.x + threadIdx.x; e < N_EDGES; e += stride) {
        int s, d;
        if (i64) { s = ep[2 * e]; d = ep[2 * (N_EDGES + e)]; }
        else     { s = ep[e];     d = ep[N_EDGES + e]; }
        int pos = atomicAdd(&nextp[d], 1);
        colidx[pos] = s;
    }
}

// ---------------- GEMM: out[r,c] = (sum_k H[r,k]*W[k,c] + bias[c]) * dinv[r] ----------------
// 64x64 tile per 256-thread block, 4x4 register tile per thread, K chunked by 64.
__global__ __launch_bounds__(256) void gemm_kernel(
    const float* __restrict__ H, const float* __restrict__ W,
    const float* __restrict__ bias, const float* __restrict__ dinvv,
    float* __restrict__ out, int n, int din, int dout)
{
    __shared__ float hs[64 * 65];
    __shared__ float Ws[64 * 64];
    int row0 = blockIdx.x * 64;
    int col0 = blockIdx.y * 64;
    int tid = threadIdx.x;
    int ty = tid >> 4, tx = tid & 15;
    float acc[4][4] = {};
    int wcols = dout - col0;
    if (wcols > 64) wcols = 64;

    for (int kc = 0; kc < din; kc += 64) {
        int kl = din - kc;
        if (kl > 64) kl = 64;
        __syncthreads();
        // stage H chunk [64][kl], row-major stride 65
        for (int idx = tid; idx < 64 * kl; idx += 256) {
            int r = idx / kl;
            int k = idx - r * kl;
            int gr = row0 + r;
            hs[r * 65 + k] = (gr < n) ? H[gr * din + kc + k] : 0.f;
        }
        // stage W chunk [kl][64]
        for (int idx = tid; idx < (kl << 6); idx += 256) {
            int k = idx >> 6, c = idx & 63;
            Ws[idx] = (c < wcols) ? W[(kc + k) * dout + col0 + c] : 0.f;
        }
        __syncthreads();
        for (int k = 0; k < kl; ++k) {
            float a0 = hs[(ty * 4 + 0) * 65 + k];
            float a1 = hs[(ty * 4 + 1) * 65 + k];
            float a2 = hs[(ty * 4 + 2) * 65 + k];
            float a3 = hs[(ty * 4 + 3) * 65 + k];
            float4 bq = *(const float4*)&Ws[(k << 6) + tx * 4];
            acc[0][0] = fmaf(a0, bq.x, acc[0][0]);
            acc[0][1] = fmaf(a0, bq.y, acc[0][1]);
            acc[0][2] = fmaf(a0, bq.z, acc[0][2]);
            acc[0][3] = fmaf(a0, bq.w, acc[0][3]);
            acc[1][0] = fmaf(a1, bq.x, acc[1][0]);
            acc[1][1] = fmaf(a1, bq.y, acc[1][1]);
            acc[1][2] = fmaf(a1, bq.z, acc[1][2]);
            acc[1][3] = fmaf(a1, bq.w, acc[1][3]);
            acc[2][0] = fmaf(a2, bq.x, acc[2][0]);
            acc[2][1] = fmaf(a2, bq.y, acc[2][1]);
            acc[2][2] = fmaf(a2, bq.z, acc[2][2]);
            acc[2][3] = fmaf(a2, bq.w, acc[2][3]);
            acc[3][0] = fmaf(a3, bq.x, acc[3][0]);
            acc[3][1] = fmaf(a3, bq.y, acc[3][1]);
            acc[3][2] = fmaf(a3, bq.z, acc[3][2]);
            acc[3][3] = fmaf(a3, bq.w, acc[3][3]);
        }
    }
    float bv[4];
#pragma unroll
    for (int cc = 0; cc < 4; cc++) {
        int c = col0 + tx * 4 + cc;
        bv[cc] = (c < dout) ? bias[c] : 0.f;
    }
#pragma unroll
    for (int rr = 0; rr < 4; rr++) {
        int r = row0 + ty * 4 + rr;
        if (r < n) {
            float di = dinvv[r];
#pragma unroll
            for (int cc = 0; cc < 4; cc++) {
                int c = col0 + tx * 4 + cc;
                if (c < dout) out[r * dout + c] = (acc[rr][cc] + bv[cc]) * di;
            }
        }
    }
}

// ---------------- BN fold into next GEMM: Wf = scale⊙W, bf = shift@W ----------------
__global__ void fold_kernel(const float* __restrict__ ssum, const float* __restrict__ ssq,
                            const float* __restrict__ g, const float* __restrict__ be,
                            const float* __restrict__ W, float* __restrict__ Wf,
                            float* __restrict__ bf, int din, int dout)
{
    __shared__ float scale_s[128], shift_s[128];
    int t = threadIdx.x;
    if (t < din) {
        float mu = ssum[t] * (1.0f / N_NODES);
        float var = ssq[t] * (1.0f / N_NODES) - mu * mu;
        float iv = rsqrtf(var + BN_EPS);
        float sc = g[t] * iv;
        scale_s[t] = sc;
        shift_s[t] = be[t] - mu * sc;
    }
    __syncthreads();
    for (int idx = t; idx < din * dout; idx += 256) {
        int k = idx / dout;
        Wf[idx] = scale_s[k] * W[idx];
    }
    for (int c = t; c < dout; c += 256) {
        float s = 0.f;
        for (int k = 0; k < din; k++) s += shift_s[k] * W[k * dout + c];
        bf[c] = s;
    }
}

// ---------------- aggregation: h = relu(dinv[i]*(self + sum_j XWs[j]) + b) + stats ----------------
template <int DOUT>
__global__ __launch_bounds__(256) void agg_kernel(
    const float* __restrict__ XWs, const int* __restrict__ rowptr,
    const int* __restrict__ colidx, const float* __restrict__ dinv,
    const float* __restrict__ bconv, float* __restrict__ hout,
    float* __restrict__ csum, float* __restrict__ csq)
{
    constexpr int VPL = (DOUT == 128) ? 2 : 1;
    int lane = threadIdx.x & 63;
    int wid = threadIdx.x >> 6;
    int gwave = blockIdx.x * 4 + wid;
    int nwave = gridDim.x * 4;

    float lsum[VPL];
    float lsq[VPL];
#pragma unroll
    for (int v = 0; v < VPL; v++) { lsum[v] = 0.f; lsq[v] = 0.f; }

    if constexpr (DOUT == 32) {
        int f = lane & 31, part = lane >> 5;
        float b = bconv[f];
        for (int i = gwave; i < N_NODES; i += nwave) {
            int iu = __builtin_amdgcn_readfirstlane(i);
            int start = rowptr[iu], end = rowptr[iu + 1];
            float selfv = XWs[iu * 32 + f];
            float acc = part ? 0.f : selfv;
            int e = start + part;
            for (; e + 6 < end; e += 8) {
                int j0 = colidx[e], j1 = colidx[e + 2], j2 = colidx[e + 4], j3 = colidx[e + 6];
                acc += XWs[j0 * 32 + f];
                acc += XWs[j1 * 32 + f];
                acc += XWs[j2 * 32 + f];
                acc += XWs[j3 * 32 + f];
            }
            for (; e < end; e += 2) acc += XWs[colidx[e] * 32 + f];
            acc += __shfl_xor(acc, 32);
            if (part == 0) {
                float h = fmaxf(fmaf(dinv[iu], acc, b), 0.f);
                hout[iu * 32 + f] = h;
                lsum[0] += h;
                lsq[0] += h * h;
            }
        }
    } else if constexpr (DOUT == 64) {
        float b = bconv[lane];
        for (int i = gwave; i < N_NODES; i += nwave) {
            int iu = __builtin_amdgcn_readfirstlane(i);
            int start = rowptr[iu], end = rowptr[iu + 1];
            float acc = XWs[iu * 64 + lane];
            int e = start;
            for (; e + 4 <= end; e += 4) {
                int j0 = colidx[e], j1 = colidx[e + 1], j2 = colidx[e + 2], j3 = colidx[e + 3];
                acc += XWs[j0 * 64 + lane];
                acc += XWs[j1 * 64 + lane];
                acc += XWs[j2 * 64 + lane];
                acc += XWs[j3 * 64 + lane];
            }
            for (; e < end; ++e) acc += XWs[colidx[e] * 64 + lane];
            float h = fmaxf(fmaf(dinv[iu], acc, b), 0.f);
            hout[iu * 64 + lane] = h;
            lsum[0] += h;
            lsq[0] += h * h;
        }
    } else { // DOUT == 128
        float b0 = bconv[lane], b1 = bconv[lane + 64];
        for (int i = gwave; i < N_NODES; i += nwave) {
            int iu = __builtin_amdgcn_readfirstlane(i);
            int start = rowptr[iu], end = rowptr[iu + 1];
            float acc0 = XWs[iu * 128 + lane];
            float acc1 = XWs[iu * 128 + 64 + lane];
            int e = start;
            for (; e + 4 <= end; e += 4) {
                int j0 = colidx[e], j1 = colidx[e + 1], j2 = colidx[e + 2], j3 = colidx[e + 3];
                acc0 += XWs[j0 * 128 + lane];
                acc1 += XWs[j0 * 128 + 64 + lane];
                acc0 += XWs[j1 * 128 + lane];
                acc1 += XWs[j1 * 128 + 64 + lane];
                acc0 += XWs[j2 * 128 + lane];
                acc1 += XWs[j2 * 128 + 64 + lane];
                acc0 += XWs[j3 * 128 + lane];
                acc1 += XWs[j3 * 128 + 64 + lane];
            }
            for (; e < end; ++e) {
                int j = colidx[e];
                acc0 += XWs[j * 128 + lane];
                acc1 += XWs[j * 128 + 64 + lane];
            }
            float di = dinv[iu];
            float h0 = fmaxf(fmaf(di, acc0, b0), 0.f);
            float h1 = fmaxf(fmaf(di, acc1, b1), 0.f);
            hout[iu * 128 + lane] = h0;
            hout[iu * 128 + 64 + lane] = h1;
            lsum[0] += h0; lsq[0] += h0 * h0;
            lsum[1] += h1; lsq[1] += h1 * h1;
        }
    }

    // block-level stats reduction, then one global atomic per feature per block
    __shared__ float ssum_s[DOUT], ssq_s[DOUT];
    if (threadIdx.x < DOUT) { ssum_s[threadIdx.x] = 0.f; ssq_s[threadIdx.x] = 0.f; }
    __syncthreads();
    if constexpr (DOUT == 32) {
        if ((lane >> 5) == 0) {
            atomicAdd(&ssum_s[lane & 31], lsum[0]);
            atomicAdd(&ssq_s[lane & 31], lsq[0]);
        }
    } else if constexpr (DOUT == 64) {
        atomicAdd(&ssum_s[lane], lsum[0]);
        atomicAdd(&ssq_s[lane], lsq[0]);
    } else {
        atomicAdd(&ssum_s[lane], lsum[0]);
        atomicAdd(&ssq_s[lane], lsq[0]);
        atomicAdd(&ssum_s[lane + 64], lsum[1]);
        atomicAdd(&ssq_s[lane + 64], lsq[1]);
    }
    __syncthreads();
    if (threadIdx.x < DOUT) {
        atomicAdd(&csum[threadIdx.x], ssum_s[threadIdx.x]);
        atomicAdd(&csq[threadIdx.x], ssq_s[threadIdx.x]);
    }
}

// ---------------- final: BN4 normalize -> h output, classifier -> logits ----------------
__global__ __launch_bounds__(256) void final_kernel(
    const float* __restrict__ h4, const float* __restrict__ ssum,
    const float* __restrict__ ssq, const float* __restrict__ g,
    const float* __restrict__ be, const float* __restrict__ Wc,
    const float* __restrict__ bc, float* __restrict__ out_logits,
    float* __restrict__ out_h)
{
    __shared__ float sc[32], sh[32], Wcs[160], bcs[5];
    int t = threadIdx.x;
    if (t < 32) {
        float mu = ssum[t] * (1.0f / N_NODES);
        float var = ssq[t] * (1.0f / N_NODES) - mu * mu;
        float iv = rsqrtf(var + BN_EPS);
        float s = g[t] * iv;
        sc[t] = s;
        sh[t] = be[t] - mu * s;
    }
    if (t < 160) Wcs[t] = Wc[t];
    if (t < 5) bcs[t] = bc[t];
    __syncthreads();
    int i = blockIdx.x * blockDim.x + t;
    if (i >= N_NODES) return;
    float hv[32];
#pragma unroll
    for (int f0 = 0; f0 < 32; f0 += 4) {
        float4 v = *(const float4*)&h4[i * 32 + f0];
        hv[f0 + 0] = fmaf(sc[f0 + 0], v.x, sh[f0 + 0]);
        hv[f0 + 1] = fmaf(sc[f0 + 1], v.y, sh[f0 + 1]);
        hv[f0 + 2] = fmaf(sc[f0 + 2], v.z, sh[f0 + 2]);
        hv[f0 + 3] = fmaf(sc[f0 + 3], v.w, sh[f0 + 3]);
    }
#pragma unroll
    for (int f0 = 0; f0 < 32; f0 += 4) {
        float4 v = {hv[f0], hv[f0 + 1], hv[f0 + 2], hv[f0 + 3]};
        *(float4*)&out_h[i * 32 + f0] = v;
    }
    float o[5];
#pragma unroll
    for (int c = 0; c < 5; c++) o[c] = bcs[c];
#pragma unroll
    for (int f = 0; f < 32; f++) {
        float hvf = hv[f];
#pragma unroll
        for (int c = 0; c < 5; c++) o[c] = fmaf(hvf, Wcs[f * 5 + c], o[c]);
    }
#pragma unroll
    for (int c = 0; c < 5; c++) out_logits[i * 5 + c] = o[c];
}

extern "C" void kernel_launch(void* const* d_in, const int* in_sizes, int n_in,
                              void* d_out, int out_size, void* d_ws, size_t ws_size,
                              hipStream_t stream)
{
    const float* x = (const float*)d_in[0];
    const int* ei = (const int*)d_in[1];
    const float* W1 = (const float*)d_in[2];
    const float* b1 = (const float*)d_in[3];
    const float* g1 = (const float*)d_in[4];
    const float* be1 = (const float*)d_in[5];
    const float* W2 = (const float*)d_in[6];
    const float* b2 = (const float*)d_in[7];
    const float* g2 = (const float*)d_in[8];
    const float* be2 = (const float*)d_in[9];
    const float* W3 = (const float*)d_in[10];
    const float* b3 = (const float*)d_in[11];
    const float* g3 = (const float*)d_in[12];
    const float* be3 = (const float*)d_in[13];
    const float* W4 = (const float*)d_in[14];
    const float* b4 = (const float*)d_in[15];
    const float* g4 = (const float*)d_in[16];
    const float* be4 = (const float*)d_in[17];
    const float* Wc = (const float*)d_in[18];
    const float* bc = (const float*)d_in[19];

    char* ws = (char*)d_ws;
    size_t off = 0;
    auto alloc = [&](size_t bytes) -> void* {
        void* p = ws + off;
        off += (bytes + 255) & ~(size_t)255;
        return p;
    };
    int* cnt = (int*)alloc((size_t)N_NODES * 4);
    int* rowptr = (int*)alloc((size_t)(N_NODES + 1) * 4);
    int* nextp = (int*)alloc((size_t)N_NODES * 4);
    int* colidx = (int*)alloc((size_t)N_EDGES * 4);
    float* dinv = (float*)alloc((size_t)N_NODES * 4);
    int* bsum = (int*)alloc(128 * 4);
    int* bscan = (int*)alloc(128 * 4);
    int* flag = (int*)alloc(256);
    float* statszone = (float*)alloc(9 * 128 * 4);
    float* csum1 = statszone + 0 * 128;
    float* csq1 = statszone + 1 * 128;
    float* csum2 = statszone + 2 * 128;
    float* csq2 = statszone + 3 * 128;
    float* csum3 = statszone + 4 * 128;
    float* csq3 = statszone + 5 * 128;
    float* csum4 = statszone + 6 * 128;
    float* csq4 = statszone + 7 * 128;
    float* zerobias = statszone + 8 * 128;
    float* Wf = (float*)alloc(128 * 128 * 4);
    float* bf = (float*)alloc(128 * 4);
    float* bufA = (float*)alloc((size_t)N_NODES * 64 * 4);
    float* bufB = (float*)alloc((size_t)N_NODES * 128 * 4);
    float* bufC = (float*)alloc((size_t)N_NODES * 128 * 4);
    if (off > ws_size) return; // workspace too small: fail loudly via validation

    hipMemsetAsync(cnt, 0, (size_t)N_NODES * 4, stream);
    hipMemsetAsync(statszone, 0, 9 * 128 * 4, stream);

    detect_kernel<<<1, 256, 0, stream>>>(ei, flag);
    hist_kernel<<<1024, 256, 0, stream>>>(ei, flag, cnt);
    scan1_kernel<<<98, 256, 0, stream>>>(cnt, rowptr, bsum);
    scan2_kernel<<<1, 128, 0, stream>>>(bsum, bscan, 98);
    scan3_kernel<<<98, 256, 0, stream>>>(rowptr, bscan, cnt, nextp, dinv);
    fill_kernel<<<1024, 256, 0, stream>>>(ei, flag, nextp, colidx);

    const int GEMM_RB = (N_NODES + 63) / 64; // 1563

    // Layer 1: x[N,39] @ W1 -> XWs1 (bufC), agg -> h1relu (bufA)
    gemm_kernel<<<dim3(GEMM_RB, 1), 256, 0, stream>>>(x, W1, zerobias, dinv, bufC, N_NODES, 39, 64);
    agg_kernel<64><<<2048, 256, 0, stream>>>(bufC, rowptr, colidx, dinv, b1, bufA, csum1, csq1);

    // Layer 2
    fold_kernel<<<1, 256, 0, stream>>>(csum1, csq1, g1, be1, W2, Wf, bf, 64, 128);
    gemm_kernel<<<dim3(GEMM_RB, 2), 256, 0, stream>>>(bufA, Wf, bf, dinv, bufC, N_NODES, 64, 128);
    agg_kernel<128><<<2048, 256, 0, stream>>>(bufC, rowptr, colidx, dinv, b2, bufB, csum2, csq2);

    // Layer 3
    fold_kernel<<<1, 256, 0, stream>>>(csum2, csq2, g2, be2, W3, Wf, bf, 128, 64);
    gemm_kernel<<<dim3(GEMM_RB, 1), 256, 0, stream>>>(bufB, Wf, bf, dinv, bufC, N_NODES, 128, 64);
    agg_kernel<64><<<2048, 256, 0, stream>>>(bufC, rowptr, colidx, dinv, b3, bufA, csum3, csq3);

    // Layer 4
    fold_kernel<<<1, 256, 0, stream>>>(csum3, csq3, g3, be3, W4, Wf, bf, 64, 32);
    gemm_kernel<<<dim3(GEMM_RB, 1), 256, 0, stream>>>(bufA, Wf, bf, dinv, bufC, N_NODES, 64, 32);
    agg_kernel<32><<<2048, 256, 0, stream>>>(bufC, rowptr, colidx, dinv, b4, bufB, csum4, csq4);

    // Final: BN4 + classifier
    float* out_logits = (float*)d_out;
    float* out_h = (float*)d_out + (size_t)N_NODES * 5;
    final_kernel<<<(N_NODES + 255) / 256, 256, 0, stream>>>(bufB, csum4, csq4, g4, be4,
                                                            Wc, bc, out_logits, out_h);
}

// Round 2
// 530.229 us; speedup vs baseline: 1.6030x; 1.6030x over previous
//
#include <hip/hip_runtime.h>

typedef unsigned int uint;
typedef unsigned short ushort;

#define N_NODES 100000
#define N_EDGES 1600000
#define NB_C 256
#define TILE_C ((N_EDGES + NB_C - 1) / NB_C)
#define NB_D ((N_NODES + 511) / 512)
#define GEMM_RB ((N_NODES + 63) / 64)
#define AGG_GRID 2048
constexpr float BN_EPS = 1e-5f;

__device__ __forceinline__ float bflo(uint w) { return __uint_as_float(w << 16); }
__device__ __forceinline__ float bfhi(uint w) { return __uint_as_float(w & 0xffff0000u); }
__device__ __forceinline__ ushort f2bf(float x) {
    uint u = __float_as_uint(x);
    uint r = (u + 0x7fffu + ((u >> 16) & 1u)) >> 16;
    return (ushort)r;
}
__device__ __forceinline__ uint pack2(float a, float b) {
    return (uint)f2bf(a) | ((uint)f2bf(b) << 16);
}

// ---------------- edge_index dtype detection (int32 vs int64) ----------------
__global__ void detect_kernel(const int* __restrict__ ep, int* __restrict__ flag)
{
    __shared__ int cnt;
    if (threadIdx.x == 0) cnt = 0;
    __syncthreads();
    int nz = 0;
    for (int k = threadIdx.x; k < 1024; k += blockDim.x)
        if (ep[2 * k + 1] != 0) nz++;
    atomicAdd(&cnt, nz);
    __syncthreads();
    if (threadIdx.x == 0) *flag = (cnt == 0) ? 1 : 0;
}

// ---------------- CSR build: atomic-free bucket sort ----------------
// A: per-block LDS histogram over coarse bins (dst>>9)
__global__ __launch_bounds__(256) void coarseA_kernel(const int* __restrict__ ep,
                                                      const int* __restrict__ flag,
                                                      uint* __restrict__ ch)
{
    __shared__ uint lh[256];
    int t = threadIdx.x, blk = blockIdx.x;
    lh[t] = 0;
    __syncthreads();
    bool i64 = (*flag != 0);
    int start = blk * TILE_C;
    int end = start + TILE_C;
    if (end > N_EDGES) end = N_EDGES;
    for (int e = start + t; e < end; e += 256) {
        int d = i64 ? ep[2 * (N_EDGES + e)] : ep[N_EDGES + e];
        atomicAdd(&lh[d >> 9], 1u);
    }
    __syncthreads();
    ch[t * NB_C + blk] = lh[t];
}

// B: scan ch (bin-major) into global offsets; bucketBase[bin]
__global__ void scanB_kernel(uint* __restrict__ ch, uint* __restrict__ bucketBase)
{
    __shared__ uint tot[256];
    int t = threadIdx.x;
    uint s = 0;
    for (int i = 0; i < NB_C; i++) s += ch[t * NB_C + i];
    tot[t] = s;
    __syncthreads();
    for (int off = 1; off < 256; off <<= 1) {
        uint add = (t >= off) ? tot[t - off] : 0u;
        __syncthreads();
        tot[t] += add;
        __syncthreads();
    }
    uint base = tot[t] - s;
    bucketBase[t] = base;
    if (t == 255) bucketBase[256] = base + s;
    uint run = base;
    for (int i = 0; i < NB_C; i++) {
        uint c = ch[t * NB_C + i];
        ch[t * NB_C + i] = run;
        run += c;
    }
}

// C: scatter edges into coarse buckets (LDS running offsets)
__global__ __launch_bounds__(256) void scatterC_kernel(const int* __restrict__ ep,
                                                       const int* __restrict__ flag,
                                                       const uint* __restrict__ ch,
                                                       int2* __restrict__ pair)
{
    __shared__ uint loff[256];
    int t = threadIdx.x, blk = blockIdx.x;
    loff[t] = ch[t * NB_C + blk];
    __syncthreads();
    bool i64 = (*flag != 0);
    int start = blk * TILE_C;
    int end = start + TILE_C;
    if (end > N_EDGES) end = N_EDGES;
    for (int e = start + t; e < end; e += 256) {
        int s, d;
        if (i64) { s = ep[2 * e]; d = ep[2 * (N_EDGES + e)]; }
        else     { s = ep[e];     d = ep[N_EDGES + e]; }
        uint pos = atomicAdd(&loff[d >> 9], 1u);
        pair[pos] = make_int2(s, d);
    }
}

// D: per-bucket (512 dst) LDS counting sort -> rowptr, dinv, colidx
__global__ __launch_bounds__(256) void bucketD_kernel(const int2* __restrict__ pair,
                                                      const uint* __restrict__ bucketBase,
                                                      int* __restrict__ rowptr,
                                                      float* __restrict__ dinv,
                                                      int* __restrict__ colidx)
{
    __shared__ uint cnt[512], offp[512], s2[256];
    int bin = blockIdx.x, t = threadIdx.x;
    cnt[t] = 0; cnt[t + 256] = 0;
    __syncthreads();
    uint lo = bucketBase[bin], hi = bucketBase[bin + 1];
    for (uint p = lo + t; p < hi; p += 256)
        atomicAdd(&cnt[pair[p].y & 511], 1u);
    __syncthreads();
    uint a = cnt[2 * t], b = cnt[2 * t + 1];
    s2[t] = a + b;
    __syncthreads();
    for (int off = 1; off < 256; off <<= 1) {
        uint add = (t >= off) ? s2[t - off] : 0u;
        __syncthreads();
        s2[t] += add;
        __syncthreads();
    }
    uint excl = s2[t] - (a + b);
    offp[2 * t] = excl;
    offp[2 * t + 1] = excl + a;
    __syncthreads();
    for (int k = t; k < 512; k += 256) {
        int d = bin * 512 + k;
        if (d < N_NODES) {
            rowptr[d] = (int)(lo + offp[k]);
            dinv[d] = rsqrtf((float)(cnt[k] + 1));
        }
    }
    if (bin == 0 && t == 0) rowptr[N_NODES] = N_EDGES;
    __syncthreads();
    for (uint p = lo + t; p < hi; p += 256) {
        int2 pr = pair[p];
        uint pos = lo + atomicAdd(&offp[pr.y & 511], 1u);
        colidx[pos] = pr.x;
    }
}

// ---------------- small prep kernels ----------------
__global__ void prepW1_kernel(const float* __restrict__ W1, float* __restrict__ W1p)
{
    int idx = blockIdx.x * 256 + threadIdx.x;
    if (idx < 40 * 64) W1p[idx] = ((idx >> 6) < 39) ? W1[idx] : 0.f;
}

// xs[i][c] = bf16(dinv[i] * x[i][c]) padded to 40 cols
__global__ __launch_bounds__(256) void xscale_kernel(const float* __restrict__ x,
                                                     const float* __restrict__ dinv,
                                                     ushort* __restrict__ xs)
{
    int idx = blockIdx.x * 256 + threadIdx.x;
    if (idx >= N_NODES * 40) return;
    int i = idx / 40;
    int c = idx - i * 40;
    float v = (c < 39) ? x[i * 39 + c] * dinv[i] : 0.f;
    xs[idx] = f2bf(v);
}

// ---------------- aggregation kernels (bf16 gather, fp32 accumulate) ----------------
// agg1: a1 = P x (40-dim padded), plus rowsumP_i = sum_j P_ij
__global__ __launch_bounds__(256) void agg1_kernel(
    const uint* __restrict__ xs, const int* __restrict__ rowptr,
    const int* __restrict__ colidx, const float* __restrict__ dinv,
    float2* __restrict__ outA, float* __restrict__ rowsumP)
{
    int lane = threadIdx.x & 63, wid = threadIdx.x >> 6;
    int part = lane >> 5, idx = lane & 31;
    bool feat = idx < 20, dlane = (idx == 20);
    int gw = blockIdx.x * 4 + wid, nw = gridDim.x * 4;
    for (int i = gw; i < N_NODES; i += nw) {
        int iu = __builtin_amdgcn_readfirstlane(i);
        int s0 = rowptr[iu], e0 = rowptr[iu + 1];
        float ax = 0.f, ay = 0.f, ad = 0.f;
        if (!part && feat) { uint w = xs[iu * 20 + idx]; ax = bflo(w); ay = bfhi(w); }
        int e = s0 + part;
        for (; e + 6 < e0; e += 8) {
            int j0 = colidx[e], j1 = colidx[e + 2], j2 = colidx[e + 4], j3 = colidx[e + 6];
            if (feat) {
                uint w0 = xs[j0 * 20 + idx], w1 = xs[j1 * 20 + idx];
                uint w2 = xs[j2 * 20 + idx], w3 = xs[j3 * 20 + idx];
                ax += bflo(w0); ay += bfhi(w0);
                ax += bflo(w1); ay += bfhi(w1);
                ax += bflo(w2); ay += bfhi(w2);
                ax += bflo(w3); ay += bfhi(w3);
            } else if (dlane) {
                ad += dinv[j0] + dinv[j1] + dinv[j2] + dinv[j3];
            }
        }
        for (; e < e0; e += 2) {
            int j = colidx[e];
            if (feat) { uint w = xs[j * 20 + idx]; ax += bflo(w); ay += bfhi(w); }
            else if (dlane) ad += dinv[j];
        }
        ax += __shfl_xor(ax, 32);
        ay += __shfl_xor(ay, 32);
        ad += __shfl_xor(ad, 32);
        float di = dinv[iu];
        float dtot = __shfl(ad, 20);
        if (!part && feat) outA[iu * 20 + idx] = make_float2(di * ax, di * ay);
        if (lane == 0) rowsumP[iu] = di * (dtot + di);
    }
}

// agg_only64: a = P z (z stored bf16 prescaled by dinv), out fp32
__global__ __launch_bounds__(256) void agg_only64_kernel(
    const uint* __restrict__ zs, const int* __restrict__ rowptr,
    const int* __restrict__ colidx, const float* __restrict__ dinv,
    float2* __restrict__ out)
{
    int lane = threadIdx.x & 63, wid = threadIdx.x >> 6;
    int part = lane >> 5, fl = lane & 31;
    int gw = blockIdx.x * 4 + wid, nw = gridDim.x * 4;
    for (int i = gw; i < N_NODES; i += nw) {
        int iu = __builtin_amdgcn_readfirstlane(i);
        int s0 = rowptr[iu], e0 = rowptr[iu + 1];
        float ax = 0.f, ay = 0.f;
        if (!part) { uint w = zs[iu * 32 + fl]; ax = bflo(w); ay = bfhi(w); }
        int e = s0 + part;
        for (; e + 6 < e0; e += 8) {
            int j0 = colidx[e], j1 = colidx[e + 2], j2 = colidx[e + 4], j3 = colidx[e + 6];
            uint w0 = zs[j0 * 32 + fl], w1 = zs[j1 * 32 + fl];
            uint w2 = zs[j2 * 32 + fl], w3 = zs[j3 * 32 + fl];
            ax += bflo(w0); ay += bfhi(w0);
            ax += bflo(w1); ay += bfhi(w1);
            ax += bflo(w2); ay += bfhi(w2);
            ax += bflo(w3); ay += bfhi(w3);
        }
        for (; e < e0; e += 2) {
            uint w = zs[colidx[e] * 32 + fl];
            ax += bflo(w); ay += bfhi(w);
        }
        ax += __shfl_xor(ax, 32);
        ay += __shfl_xor(ay, 32);
        if (!part) {
            float di = dinv[iu];
            out[iu * 32 + fl] = make_float2(di * ax, di * ay);
        }
    }
}

// agg_relu64: t = relu(P z + b), stats partials
__global__ __launch_bounds__(256) void agg_relu64_kernel(
    const uint* __restrict__ zs, const int* __restrict__ rowptr,
    const int* __restrict__ colidx, const float* __restrict__ dinv,
    const float* __restrict__ bias, float2* __restrict__ outT,
    float* __restrict__ Psum, float* __restrict__ Psq)
{
    int lane = threadIdx.x & 63, wid = threadIdx.x >> 6;
    int part = lane >> 5, fl = lane & 31;
    int gw = blockIdx.x * 4 + wid, nw = gridDim.x * 4;
    float bx = bias[2 * fl], by = bias[2 * fl + 1];
    float lsx = 0.f, lsy = 0.f, lqx = 0.f, lqy = 0.f;
    for (int i = gw; i < N_NODES; i += nw) {
        int iu = __builtin_amdgcn_readfirstlane(i);
        int s0 = rowptr[iu], e0 = rowptr[iu + 1];
        float ax = 0.f, ay = 0.f;
        if (!part) { uint w = zs[iu * 32 + fl]; ax = bflo(w); ay = bfhi(w); }
        int e = s0 + part;
        for (; e + 6 < e0; e += 8) {
            int j0 = colidx[e], j1 = colidx[e + 2], j2 = colidx[e + 4], j3 = colidx[e + 6];
            uint w0 = zs[j0 * 32 + fl], w1 = zs[j1 * 32 + fl];
            uint w2 = zs[j2 * 32 + fl], w3 = zs[j3 * 32 + fl];
            ax += bflo(w0); ay += bfhi(w0);
            ax += bflo(w1); ay += bfhi(w1);
            ax += bflo(w2); ay += bfhi(w2);
            ax += bflo(w3); ay += bfhi(w3);
        }
        for (; e < e0; e += 2) {
            uint w = zs[colidx[e] * 32 + fl];
            ax += bflo(w); ay += bfhi(w);
        }
        ax += __shfl_xor(ax, 32);
        ay += __shfl_xor(ay, 32);
        if (!part) {
            float di = dinv[iu];
            float tx_ = fmaxf(fmaf(di, ax, bx), 0.f);
            float ty_ = fmaxf(fmaf(di, ay, by), 0.f);
            outT[iu * 32 + fl] = make_float2(tx_, ty_);
            lsx += tx_; lsy += ty_;
            lqx += tx_ * tx_; lqy += ty_ * ty_;
        }
    }
    __shared__ float ssum[64], ssq[64];
    if (threadIdx.x < 64) { ssum[threadIdx.x] = 0.f; ssq[threadIdx.x] = 0.f; }
    __syncthreads();
    if (!part) {
        atomicAdd(&ssum[2 * fl], lsx); atomicAdd(&ssum[2 * fl + 1], lsy);
        atomicAdd(&ssq[2 * fl], lqx);  atomicAdd(&ssq[2 * fl + 1], lqy);
    }
    __syncthreads();
    if (threadIdx.x < 64) {
        Psum[threadIdx.x * gridDim.x + blockIdx.x] = ssum[threadIdx.x];
        Psq[threadIdx.x * gridDim.x + blockIdx.x] = ssq[threadIdx.x];
    }
}

// agg_relu32: t = relu(P z + b), 4 edges per wave-step, stats partials
__global__ __launch_bounds__(256) void agg_relu32_kernel(
    const uint* __restrict__ zs, const int* __restrict__ rowptr,
    const int* __restrict__ colidx, const float* __restrict__ dinv,
    const float* __restrict__ bias, float2* __restrict__ outT,
    float* __restrict__ Psum, float* __restrict__ Psq)
{
    int lane = threadIdx.x & 63, wid = threadIdx.x >> 6;
    int part = lane >> 4, fl = lane & 15;
    int gw = blockIdx.x * 4 + wid, nw = gridDim.x * 4;
    float bx = bias[2 * fl], by = bias[2 * fl + 1];
    float lsx = 0.f, lsy = 0.f, lqx = 0.f, lqy = 0.f;
    for (int i = gw; i < N_NODES; i += nw) {
        int iu = __builtin_amdgcn_readfirstlane(i);
        int s0 = rowptr[iu], e0 = rowptr[iu + 1];
        float ax = 0.f, ay = 0.f;
        if (part == 0) { uint w = zs[iu * 16 + fl]; ax = bflo(w); ay = bfhi(w); }
        int e = s0 + part;
        for (; e + 12 < e0; e += 16) {
            int j0 = colidx[e], j1 = colidx[e + 4], j2 = colidx[e + 8], j3 = colidx[e + 12];
            uint w0 = zs[j0 * 16 + fl], w1 = zs[j1 * 16 + fl];
            uint w2 = zs[j2 * 16 + fl], w3 = zs[j3 * 16 + fl];
            ax += bflo(w0); ay += bfhi(w0);
            ax += bflo(w1); ay += bfhi(w1);
            ax += bflo(w2); ay += bfhi(w2);
            ax += bflo(w3); ay += bfhi(w3);
        }
        for (; e < e0; e += 4) {
            uint w = zs[colidx[e] * 16 + fl];
            ax += bflo(w); ay += bfhi(w);
        }
        ax += __shfl_xor(ax, 16); ax += __shfl_xor(ax, 32);
        ay += __shfl_xor(ay, 16); ay += __shfl_xor(ay, 32);
        if (lane < 16) {
            float di = dinv[iu];
            float tx_ = fmaxf(fmaf(di, ax, bx), 0.f);
            float ty_ = fmaxf(fmaf(di, ay, by), 0.f);
            outT[iu * 16 + fl] = make_float2(tx_, ty_);
            lsx += tx_; lsy += ty_;
            lqx += tx_ * tx_; lqy += ty_ * ty_;
        }
    }
    __shared__ float ssum[32], ssq[32];
    if (threadIdx.x < 32) { ssum[threadIdx.x] = 0.f; ssq[threadIdx.x] = 0.f; }
    __syncthreads();
    if (lane < 16) {
        atomicAdd(&ssum[2 * fl], lsx); atomicAdd(&ssum[2 * fl + 1], lsy);
        atomicAdd(&ssq[2 * fl], lqx);  atomicAdd(&ssq[2 * fl + 1], lqy);
    }
    __syncthreads();
    if (threadIdx.x < 32) {
        Psum[threadIdx.x * gridDim.x + blockIdx.x] = ssum[threadIdx.x];
        Psq[threadIdx.x * gridDim.x + blockIdx.x] = ssq[threadIdx.x];
    }
}

// ---------------- GEMM with mode-specific epilogue ----------------
// MODE 0: t=relu(acc+bias); stats; out bf16 = dinv[r]*t
// MODE 1: t=relu(acc+bias+rowsumP[r]*bias2); stats; out f32 = t
// MODE 2: z=acc+bias; out bf16 = dinv[r]*z (no relu, no stats)
template <int MODE>
__global__ __launch_bounds__(256) void gemm_kernel(
    const float* __restrict__ H, const float* __restrict__ W,
    const float* __restrict__ bias, const float* __restrict__ bias2,
    const float* __restrict__ rowsumP, const float* __restrict__ dinvv,
    float* __restrict__ outF, ushort* __restrict__ outB,
    float* __restrict__ Psum, float* __restrict__ Psq,
    int n, int din, int dout)
{
    __shared__ float hs[64 * 65];
    __shared__ float Ws[64 * 64];
    __shared__ float ssum[64], ssq[64];
    int row0 = blockIdx.x * 64;
    int col0 = blockIdx.y * 64;
    int tid = threadIdx.x;
    int ty = tid >> 4, tx = tid & 15;
    float acc[4][4] = {};
    int wcols = dout - col0;
    if (wcols > 64) wcols = 64;

    for (int kc = 0; kc < din; kc += 64) {
        int kl = din - kc;
        if (kl > 64) kl = 64;
        __syncthreads();
        for (int idx = tid; idx < 64 * kl; idx += 256) {
            int r = idx / kl;
            int k = idx - r * kl;
            int gr = row0 + r;
            hs[r * 65 + k] = (gr < n) ? H[gr * din + kc + k] : 0.f;
        }
        for (int idx = tid; idx < (kl << 6); idx += 256) {
            int k = idx >> 6, c = idx & 63;
            Ws[idx] = (c < wcols) ? W[(kc + k) * dout + col0 + c] : 0.f;
        }
        __syncthreads();
        for (int k = 0; k < kl; ++k) {
            float a0 = hs[(ty * 4 + 0) * 65 + k];
            float a1 = hs[(ty * 4 + 1) * 65 + k];
            float a2 = hs[(ty * 4 + 2) * 65 + k];
            float a3 = hs[(ty * 4 + 3) * 65 + k];
            float4 bq = *(const float4*)&Ws[(k << 6) + tx * 4];
            acc[0][0] = fmaf(a0, bq.x, acc[0][0]);
            acc[0][1] = fmaf(a0, bq.y, acc[0][1]);
            acc[0][2] = fmaf(a0, bq.z, acc[0][2]);
            acc[0][3] = fmaf(a0, bq.w, acc[0][3]);
            acc[1][0] = fmaf(a1, bq.x, acc[1][0]);
            acc[1][1] = fmaf(a1, bq.y, acc[1][1]);
            acc[1][2] = fmaf(a1, bq.z, acc[1][2]);
            acc[1][3] = fmaf(a1, bq.w, acc[1][3]);
            acc[2][0] = fmaf(a2, bq.x, acc[2][0]);
            acc[2][1] = fmaf(a2, bq.y, acc[2][1]);
            acc[2][2] = fmaf(a2, bq.z, acc[2][2]);
            acc[2][3] = fmaf(a2, bq.w, acc[2][3]);
            acc[3][0] = fmaf(a3, bq.x, acc[3][0]);
            acc[3][1] = fmaf(a3, bq.y, acc[3][1]);
            acc[3][2] = fmaf(a3, bq.z, acc[3][2]);
            acc[3][3] = fmaf(a3, bq.w, acc[3][3]);
        }
    }

    if constexpr (MODE <= 1) {
        if (tid < 64) { ssum[tid] = 0.f; ssq[tid] = 0.f; }
    }
    __syncthreads();

    float bv[4], b2v[4];
#pragma unroll
    for (int cc = 0; cc < 4; cc++) {
        int c = col0 + tx * 4 + cc;
        bv[cc] = (c < dout) ? bias[c] : 0.f;
        if constexpr (MODE == 1) b2v[cc] = (c < dout) ? bias2[c] : 0.f;
        else b2v[cc] = 0.f;
    }
    float cs[4] = {}, cq[4] = {};
#pragma unroll
    for (int rr = 0; rr < 4; rr++) {
        int r = row0 + ty * 4 + rr;
        if (r < n) {
            float tv[4];
            float rp = 0.f, scl = 1.f;
            if constexpr (MODE == 1) rp = rowsumP[r];
            else scl = dinvv[r];
#pragma unroll
            for (int cc = 0; cc < 4; cc++) {
                float v = acc[rr][cc] + bv[cc];
                if constexpr (MODE == 1) v += rp * b2v[cc];
                if constexpr (MODE <= 1) v = fmaxf(v, 0.f);
                tv[cc] = v;
                if constexpr (MODE <= 1) { cs[cc] += v; cq[cc] += v * v; }
            }
            if constexpr (MODE == 1) {
                *(float4*)&outF[(size_t)r * dout + col0 + tx * 4] =
                    make_float4(tv[0], tv[1], tv[2], tv[3]);
            } else {
                if (col0 + tx * 4 < dout) {
                    uint2 pk;
                    pk.x = pack2(scl * tv[0], scl * tv[1]);
                    pk.y = pack2(scl * tv[2], scl * tv[3]);
                    *(uint2*)&outB[(size_t)r * dout + col0 + tx * 4] = pk;
                }
            }
        }
    }
    if constexpr (MODE <= 1) {
#pragma unroll
        for (int cc = 0; cc < 4; cc++) {
            atomicAdd(&ssum[tx * 4 + cc], cs[cc]);
            atomicAdd(&ssq[tx * 4 + cc], cq[cc]);
        }
        __syncthreads();
        if (tid < 64) {
            Psum[(size_t)(col0 + tid) * gridDim.x + blockIdx.x] = ssum[tid];
            Psq[(size_t)(col0 + tid) * gridDim.x + blockIdx.x] = ssq[tid];
        }
    }
}

// ---------------- BN stat reduce -> scale/shift ----------------
__global__ __launch_bounds__(256) void reduce_bn_kernel(
    const float* __restrict__ Psum, const float* __restrict__ Psq, int nb,
    const float* __restrict__ g, const float* __restrict__ be,
    float* __restrict__ sOut, float* __restrict__ uOut)
{
    int c = blockIdx.x, t = threadIdx.x;
    float s = 0.f, q = 0.f;
    for (int i = t; i < nb; i += 256) {
        s += Psum[(size_t)c * nb + i];
        q += Psq[(size_t)c * nb + i];
    }
    __shared__ float rs[256], rq[256];
    rs[t] = s; rq[t] = q;
    __syncthreads();
    for (int off = 128; off > 0; off >>= 1) {
        if (t < off) { rs[t] += rs[t + off]; rq[t] += rq[t + off]; }
        __syncthreads();
    }
    if (t == 0) {
        float mu = rs[0] * (1.0f / N_NODES);
        float var = rq[0] * (1.0f / N_NODES) - mu * mu;
        float sv = g[c] * rsqrtf(var + BN_EPS);
        sOut[c] = sv;
        uOut[c] = be[c] - mu * sv;
    }
}

// ---------------- fold: Wf = s (row) * W ; v[c] = u @ W[:,c] ----------------
__global__ void foldW_kernel(const float* __restrict__ W, const float* __restrict__ s,
                             const float* __restrict__ u, float* __restrict__ Wf,
                             float* __restrict__ v, int din, int dout)
{
    int c = blockIdx.x, t = threadIdx.x;
    float contrib = 0.f;
    if (t < din) {
        float w = W[t * dout + c];
        Wf[t * dout + c] = s[t] * w;
        contrib = u[t] * w;
    }
    __shared__ float red[128];
    red[t] = contrib;
    __syncthreads();
    for (int off = 64; off > 0; off >>= 1) {
        if (t < off) red[t] += red[t + off];
        __syncthreads();
    }
    if (t == 0) v[c] = red[0];
}

// ---------------- final: h4 = s4*t4+u4, logits = h4@Wc+bc ----------------
__global__ __launch_bounds__(256) void final_kernel(
    const float* __restrict__ t4, const float* __restrict__ sArr,
    const float* __restrict__ uArr, const float* __restrict__ Wc,
    const float* __restrict__ bc, float* __restrict__ out_logits,
    float* __restrict__ out_h)
{
    __shared__ float sc[32], sh2[32], Wcs[160], bcs[5];
    int t = threadIdx.x;
    if (t < 32) { sc[t] = sArr[t]; sh2[t] = uArr[t]; }
    if (t < 160) Wcs[t] = Wc[t];
    if (t < 5) bcs[t] = bc[t];
    __syncthreads();
    int i = blockIdx.x * blockDim.x + t;
    if (i >= N_NODES) return;
    float hv[32];
#pragma unroll
    for (int f0 = 0; f0 < 32; f0 += 4) {
        float4 v = *(const float4*)&t4[(size_t)i * 32 + f0];
        hv[f0 + 0] = fmaf(sc[f0 + 0], v.x, sh2[f0 + 0]);
        hv[f0 + 1] = fmaf(sc[f0 + 1], v.y, sh2[f0 + 1]);
        hv[f0 + 2] = fmaf(sc[f0 + 2], v.z, sh2[f0 + 2]);
        hv[f0 + 3] = fmaf(sc[f0 + 3], v.w, sh2[f0 + 3]);
    }
#pragma unroll
    for (int f0 = 0; f0 < 32; f0 += 4) {
        float4 v = {hv[f0], hv[f0 + 1], hv[f0 + 2], hv[f0 + 3]};
        *(float4*)&out_h[(size_t)i * 32 + f0] = v;
    }
    float o[5];
#pragma unroll
    for (int c = 0; c < 5; c++) o[c] = bcs[c];
#pragma unroll
    for (int f = 0; f < 32; f++) {
        float hvf = hv[f];
#pragma unroll
        for (int c = 0; c < 5; c++) o[c] = fmaf(hvf, Wcs[f * 5 + c], o[c]);
    }
#pragma unroll
    for (int c = 0; c < 5; c++) out_logits[(size_t)i * 5 + c] = o[c];
}

extern "C" void kernel_launch(void* const* d_in, const int* in_sizes, int n_in,
                              void* d_out, int out_size, void* d_ws, size_t ws_size,
                              hipStream_t stream)
{
    const float* x = (const float*)d_in[0];
    const int* ei = (const int*)d_in[1];
    const float* W1 = (const float*)d_in[2];
    const float* b1 = (const float*)d_in[3];
    const float* g1 = (const float*)d_in[4];
    const float* be1 = (const float*)d_in[5];
    const float* W2 = (const float*)d_in[6];
    const float* b2 = (const float*)d_in[7];
    const float* g2 = (const float*)d_in[8];
    const float* be2 = (const float*)d_in[9];
    const float* W3 = (const float*)d_in[10];
    const float* b3 = (const float*)d_in[11];
    const float* g3 = (const float*)d_in[12];
    const float* be3 = (const float*)d_in[13];
    const float* W4 = (const float*)d_in[14];
    const float* b4 = (const float*)d_in[15];
    const float* g4 = (const float*)d_in[16];
    const float* be4 = (const float*)d_in[17];
    const float* Wc = (const float*)d_in[18];
    const float* bc = (const float*)d_in[19];

    char* ws = (char*)d_ws;
    size_t off = 0;
    auto alloc = [&](size_t bytes) -> void* {
        void* p = ws + off;
        off += (bytes + 255) & ~(size_t)255;
        return p;
    };
    uint* ch = (uint*)alloc(65536 * 4);
    uint* bucketBase = (uint*)alloc(257 * 4);
    int2* pair = (int2*)alloc((size_t)N_EDGES * 8);
    int* rowptr = (int*)alloc((size_t)(N_NODES + 1) * 4);
    float* dinv = (float*)alloc((size_t)N_NODES * 4);
    int* colidx = (int*)alloc((size_t)N_EDGES * 4);
    int* flag = (int*)alloc(256);
    float* rowsumP = (float*)alloc((size_t)N_NODES * 4);
    ushort* xs = (ushort*)alloc((size_t)N_NODES * 40 * 2);
    float* W1p = (float*)alloc(40 * 64 * 4);
    float* Wf = (float*)alloc(128 * 128 * 4);
    float* vB = (float*)alloc(128 * 4);
    float* sArr = (float*)alloc(128 * 4);
    float* uArr = (float*)alloc(128 * 4);
    float* Psum = (float*)alloc((size_t)128 * 2048 * 4);
    float* Psq = (float*)alloc((size_t)128 * 2048 * 4);
    float* BigA = (float*)alloc((size_t)N_NODES * 128 * 4); // a1 [N,40] then t2 [N,128], then t4 [N,32]? no: t4->BigB
    float* BigB = (float*)alloc((size_t)N_NODES * 64 * 4);  // a2, then t3, then t4
    ushort* BbfA = (ushort*)alloc((size_t)N_NODES * 64 * 2); // t1s, then z3s, then z4s
    if (off > ws_size) return;

    // ---- CSR build (atomic-free) ----
    detect_kernel<<<1, 256, 0, stream>>>(ei, flag);
    coarseA_kernel<<<NB_C, 256, 0, stream>>>(ei, flag, ch);
    scanB_kernel<<<1, 256, 0, stream>>>(ch, bucketBase);
    scatterC_kernel<<<NB_C, 256, 0, stream>>>(ei, flag, ch, pair);
    bucketD_kernel<<<NB_D, 256, 0, stream>>>(pair, bucketBase, rowptr, dinv, colidx);

    // ---- prep ----
    prepW1_kernel<<<10, 256, 0, stream>>>(W1, W1p);
    xscale_kernel<<<(N_NODES * 40 + 255) / 256, 256, 0, stream>>>(x, dinv, xs);

    // ---- Layer 1: a1 = P x ; t1 = relu(a1@W1+b1); stats1; t1s bf16 ----
    agg1_kernel<<<AGG_GRID, 256, 0, stream>>>((const uint*)xs, rowptr, colidx, dinv,
                                              (float2*)BigA, rowsumP);
    gemm_kernel<0><<<dim3(GEMM_RB, 1), 256, 0, stream>>>(
        BigA, W1p, b1, nullptr, nullptr, dinv, nullptr, BbfA, Psum, Psq, N_NODES, 40, 64);
    reduce_bn_kernel<<<64, 256, 0, stream>>>(Psum, Psq, GEMM_RB, g1, be1, sArr, uArr);
    foldW_kernel<<<128, 128, 0, stream>>>(W2, sArr, uArr, Wf, vB, 64, 128);

    // ---- Layer 2: a2 = P t1 ; t2 = relu(a2@W2f + b2 + rowsumP*v2); stats2 ----
    agg_only64_kernel<<<AGG_GRID, 256, 0, stream>>>((const uint*)BbfA, rowptr, colidx, dinv,
                                                    (float2*)BigB);
    gemm_kernel<1><<<dim3(GEMM_RB, 2), 256, 0, stream>>>(
        BigB, Wf, b2, vB, rowsumP, dinv, BigA, nullptr, Psum, Psq, N_NODES, 64, 128);
    reduce_bn_kernel<<<128, 256, 0, stream>>>(Psum, Psq, GEMM_RB, g2, be2, sArr, uArr);
    foldW_kernel<<<64, 128, 0, stream>>>(W3, sArr, uArr, Wf, vB, 128, 64);

    // ---- Layer 3: z3 = t2@W3f + v3 (bf16, dinv-scaled); t3 = relu(P z3 + b3); stats3 ----
    gemm_kernel<2><<<dim3(GEMM_RB, 1), 256, 0, stream>>>(
        BigA, Wf, vB, nullptr, nullptr, dinv, nullptr, BbfA, nullptr, nullptr, N_NODES, 128, 64);
    agg_relu64_kernel<<<AGG_GRID, 256, 0, stream>>>((const uint*)BbfA, rowptr, colidx, dinv,
                                                    b3, (float2*)BigB, Psum, Psq);
    reduce_bn_kernel<<<64, 256, 0, stream>>>(Psum, Psq, AGG_GRID, g3, be3, sArr, uArr);
    foldW_kernel<<<32, 128, 0, stream>>>(W4, sArr, uArr, Wf, vB, 64, 32);

    // ---- Layer 4: z4 = t3@W4f + v4 (bf16, dinv-scaled); t4 = relu(P z4 + b4); stats4 ----
    gemm_kernel<2><<<dim3(GEMM_RB, 1), 256, 0, stream>>>(
        BigB, Wf, vB, nullptr, nullptr, dinv, nullptr, BbfA, nullptr, nullptr, N_NODES, 64, 32);
    agg_relu32_kernel<<<AGG_GRID, 256, 0, stream>>>((const uint*)BbfA, rowptr, colidx, dinv,
                                                    b4, (float2*)BigB, Psum, Psq);
    reduce_bn_kernel<<<32, 256, 0, stream>>>(Psum, Psq, AGG_GRID, g4, be4, sArr, uArr);

    // ---- final ----
    float* out_logits = (float*)d_out;
    float* out_h = (float*)d_out + (size_t)N_NODES * 5;
    final_kernel<<<(N_NODES + 255) / 256, 256, 0, stream>>>(BigB, sArr, uArr, Wc, bc,
                                                            out_logits, out_h);
}

// Round 3
// 382.395 us; speedup vs baseline: 2.2227x; 1.3866x over previous
//
#include <hip/hip_runtime.h>

typedef unsigned int uint;
typedef unsigned short ushort;
typedef __attribute__((ext_vector_type(8))) short bf16x8;
typedef __attribute__((ext_vector_type(4))) float f32x4;

#define N_NODES 100000
#define N_EDGES 1600000
#define NB_C 256
#define TILE_C ((N_EDGES + NB_C - 1) / NB_C)
#define NB_D ((N_NODES + 511) / 512)
#define MG_GRID ((N_NODES + 63) / 64)
#define AGG_GRID 2048
constexpr float BN_EPS = 1e-5f;

__device__ __forceinline__ float bflo(uint w) { return __uint_as_float(w << 16); }
__device__ __forceinline__ float bfhi(uint w) { return __uint_as_float(w & 0xffff0000u); }
__device__ __forceinline__ ushort f2bf(float x) {
    uint u = __float_as_uint(x);
    uint r = (u + 0x7fffu + ((u >> 16) & 1u)) >> 16;
    return (ushort)r;
}
__device__ __forceinline__ uint pack2(float a, float b) {
    return (uint)f2bf(a) | ((uint)f2bf(b) << 16);
}

// ---------------- edge_index dtype detection (int32 vs int64) ----------------
__global__ void detect_kernel(const int* __restrict__ ep, int* __restrict__ flag)
{
    __shared__ int cnt;
    if (threadIdx.x == 0) cnt = 0;
    __syncthreads();
    int nz = 0;
    for (int k = threadIdx.x; k < 1024; k += blockDim.x)
        if (ep[2 * k + 1] != 0) nz++;
    atomicAdd(&cnt, nz);
    __syncthreads();
    if (threadIdx.x == 0) *flag = (cnt == 0) ? 1 : 0;
}

// ---------------- CSR build: atomic-free bucket sort ----------------
__global__ __launch_bounds__(256) void coarseA_kernel(const int* __restrict__ ep,
                                                      const int* __restrict__ flag,
                                                      uint* __restrict__ ch)
{
    __shared__ uint lh[256];
    int t = threadIdx.x, blk = blockIdx.x;
    lh[t] = 0;
    __syncthreads();
    bool i64 = (*flag != 0);
    int start = blk * TILE_C;
    int end = start + TILE_C;
    if (end > N_EDGES) end = N_EDGES;
    for (int e = start + t; e < end; e += 256) {
        int d = i64 ? ep[2 * (N_EDGES + e)] : ep[N_EDGES + e];
        atomicAdd(&lh[d >> 9], 1u);
    }
    __syncthreads();
    ch[t * NB_C + blk] = lh[t];
}

__global__ void scanB_kernel(uint* __restrict__ ch, uint* __restrict__ bucketBase)
{
    __shared__ uint tot[256];
    int t = threadIdx.x;
    uint s = 0;
    for (int i = 0; i < NB_C; i++) s += ch[t * NB_C + i];
    tot[t] = s;
    __syncthreads();
    for (int off = 1; off < 256; off <<= 1) {
        uint add = (t >= off) ? tot[t - off] : 0u;
        __syncthreads();
        tot[t] += add;
        __syncthreads();
    }
    uint base = tot[t] - s;
    bucketBase[t] = base;
    if (t == 255) bucketBase[256] = base + s;
    uint run = base;
    for (int i = 0; i < NB_C; i++) {
        uint c = ch[t * NB_C + i];
        ch[t * NB_C + i] = run;
        run += c;
    }
}

__global__ __launch_bounds__(256) void scatterC_kernel(const int* __restrict__ ep,
                                                       const int* __restrict__ flag,
                                                       const uint* __restrict__ ch,
                                                       int2* __restrict__ pair)
{
    __shared__ uint loff[256];
    int t = threadIdx.x, blk = blockIdx.x;
    loff[t] = ch[t * NB_C + blk];
    __syncthreads();
    bool i64 = (*flag != 0);
    int start = blk * TILE_C;
    int end = start + TILE_C;
    if (end > N_EDGES) end = N_EDGES;
    for (int e = start + t; e < end; e += 256) {
        int s, d;
        if (i64) { s = ep[2 * e]; d = ep[2 * (N_EDGES + e)]; }
        else     { s = ep[e];     d = ep[N_EDGES + e]; }
        uint pos = atomicAdd(&loff[d >> 9], 1u);
        pair[pos] = make_int2(s, d);
    }
}

__global__ __launch_bounds__(256) void bucketD_kernel(const int2* __restrict__ pair,
                                                      const uint* __restrict__ bucketBase,
                                                      int* __restrict__ rowptr,
                                                      float* __restrict__ dinv,
                                                      int* __restrict__ colidx)
{
    __shared__ uint cnt[512], offp[512], s2[256];
    int bin = blockIdx.x, t = threadIdx.x;
    cnt[t] = 0; cnt[t + 256] = 0;
    __syncthreads();
    uint lo = bucketBase[bin], hi = bucketBase[bin + 1];
    for (uint p = lo + t; p < hi; p += 256)
        atomicAdd(&cnt[pair[p].y & 511], 1u);
    __syncthreads();
    uint a = cnt[2 * t], b = cnt[2 * t + 1];
    s2[t] = a + b;
    __syncthreads();
    for (int off = 1; off < 256; off <<= 1) {
        uint add = (t >= off) ? s2[t - off] : 0u;
        __syncthreads();
        s2[t] += add;
        __syncthreads();
    }
    uint excl = s2[t] - (a + b);
    offp[2 * t] = excl;
    offp[2 * t + 1] = excl + a;
    __syncthreads();
    for (int k = t; k < 512; k += 256) {
        int d = bin * 512 + k;
        if (d < N_NODES) {
            rowptr[d] = (int)(lo + offp[k]);
            dinv[d] = rsqrtf((float)(cnt[k] + 1));
        }
    }
    if (bin == 0 && t == 0) rowptr[N_NODES] = N_EDGES;
    __syncthreads();
    for (uint p = lo + t; p < hi; p += 256) {
        int2 pr = pair[p];
        uint pos = lo + atomicAdd(&offp[pr.y & 511], 1u);
        colidx[pos] = pr.x;
    }
}

// ---------------- xs[i][c] = bf16(dinv[i] * x[i][c]) padded to 40 cols ----------------
__global__ __launch_bounds__(256) void xscale_kernel(const float* __restrict__ x,
                                                     const float* __restrict__ dinv,
                                                     ushort* __restrict__ xs)
{
    int idx = blockIdx.x * 256 + threadIdx.x;
    if (idx >= N_NODES * 40) return;
    int i = idx / 40;
    int c = idx - i * 40;
    float v = (c < 39) ? x[i * 39 + c] * dinv[i] : 0.f;
    xs[idx] = f2bf(v);
}

// ---------------- W fragment packing: out[((kt*CT+ct)*64+lane)*8+j] ----------------
// = bf16( W[kt*32+(lane>>4)*8+j][ct*16+(lane&15)] ), zero for k >= din
__global__ void packW_kernel(const float* __restrict__ W, ushort* __restrict__ out,
                             int din, int dout, int K)
{
    int CT = dout >> 4;
    int tot = (K >> 5) * CT * 64 * 8;
    for (int idx = blockIdx.x * 256 + threadIdx.x; idx < tot; idx += gridDim.x * 256) {
        int j = idx & 7;
        int lane = (idx >> 3) & 63;
        int slot = idx >> 9;
        int ct = slot % CT, kt = slot / CT;
        int k = kt * 32 + (lane >> 4) * 8 + j;
        int c = ct * 16 + (lane & 15);
        float v = (k < din) ? W[k * dout + c] : 0.f;
        out[idx] = f2bf(v);
    }
}

// ---------------- aggregation kernels (bf16 gather, fp32 accumulate, bf16 out) ----------------
// agg1: a1 = Ahat x -> bf16 [N,64-pad], plus rowsumP_i
__global__ __launch_bounds__(256) void agg1_kernel(
    const uint* __restrict__ xs, const int* __restrict__ rowptr,
    const int* __restrict__ colidx, const float* __restrict__ dinv,
    uint* __restrict__ outU, float* __restrict__ rowsumP)
{
    int lane = threadIdx.x & 63, wid = threadIdx.x >> 6;
    int part = lane >> 5, idx = lane & 31;
    bool feat = idx < 20, dlane = (idx == 20);
    int gw = blockIdx.x * 4 + wid, nw = gridDim.x * 4;
    for (int i = gw; i < N_NODES; i += nw) {
        int iu = __builtin_amdgcn_readfirstlane(i);
        int s0 = rowptr[iu], e0 = rowptr[iu + 1];
        float ax = 0.f, ay = 0.f, ad = 0.f;
        if (!part && feat) { uint w = xs[iu * 20 + idx]; ax = bflo(w); ay = bfhi(w); }
        int e = s0 + part;
        for (; e + 6 < e0; e += 8) {
            int j0 = colidx[e], j1 = colidx[e + 2], j2 = colidx[e + 4], j3 = colidx[e + 6];
            if (feat) {
                uint w0 = xs[j0 * 20 + idx], w1 = xs[j1 * 20 + idx];
                uint w2 = xs[j2 * 20 + idx], w3 = xs[j3 * 20 + idx];
                ax += bflo(w0); ay += bfhi(w0);
                ax += bflo(w1); ay += bfhi(w1);
                ax += bflo(w2); ay += bfhi(w2);
                ax += bflo(w3); ay += bfhi(w3);
            } else if (dlane) {
                ad += dinv[j0] + dinv[j1] + dinv[j2] + dinv[j3];
            }
        }
        for (; e < e0; e += 2) {
            int j = colidx[e];
            if (feat) { uint w = xs[j * 20 + idx]; ax += bflo(w); ay += bfhi(w); }
            else if (dlane) ad += dinv[j];
        }
        ax += __shfl_xor(ax, 32);
        ay += __shfl_xor(ay, 32);
        ad += __shfl_xor(ad, 32);
        float di = dinv[iu];
        float dtot = __shfl(ad, 20);
        if (!part) outU[iu * 32 + idx] = feat ? pack2(di * ax, di * ay) : 0u;
        if (lane == 0) rowsumP[iu] = di * (dtot + di);
    }
}

// agg_only64: a = Ahat z (z bf16 dinv-prescaled), out bf16 [N,64]
__global__ __launch_bounds__(256) void agg_only64_kernel(
    const uint* __restrict__ zs, const int* __restrict__ rowptr,
    const int* __restrict__ colidx, const float* __restrict__ dinv,
    uint* __restrict__ out)
{
    int lane = threadIdx.x & 63, wid = threadIdx.x >> 6;
    int part = lane >> 5, fl = lane & 31;
    int gw = blockIdx.x * 4 + wid, nw = gridDim.x * 4;
    for (int i = gw; i < N_NODES; i += nw) {
        int iu = __builtin_amdgcn_readfirstlane(i);
        int s0 = rowptr[iu], e0 = rowptr[iu + 1];
        float ax = 0.f, ay = 0.f;
        if (!part) { uint w = zs[iu * 32 + fl]; ax = bflo(w); ay = bfhi(w); }
        int e = s0 + part;
        for (; e + 6 < e0; e += 8) {
            int j0 = colidx[e], j1 = colidx[e + 2], j2 = colidx[e + 4], j3 = colidx[e + 6];
            uint w0 = zs[j0 * 32 + fl], w1 = zs[j1 * 32 + fl];
            uint w2 = zs[j2 * 32 + fl], w3 = zs[j3 * 32 + fl];
            ax += bflo(w0); ay += bfhi(w0);
            ax += bflo(w1); ay += bfhi(w1);
            ax += bflo(w2); ay += bfhi(w2);
            ax += bflo(w3); ay += bfhi(w3);
        }
        for (; e < e0; e += 2) {
            uint w = zs[colidx[e] * 32 + fl];
            ax += bflo(w); ay += bfhi(w);
        }
        ax += __shfl_xor(ax, 32);
        ay += __shfl_xor(ay, 32);
        if (!part) {
            float di = dinv[iu];
            out[iu * 32 + fl] = pack2(di * ax, di * ay);
        }
    }
}

// agg_relu64: t = relu(Ahat(z)+b) -> bf16 [N,64] (plain), stats partials
__global__ __launch_bounds__(256) void agg_relu64_kernel(
    const uint* __restrict__ zs, const int* __restrict__ rowptr,
    const int* __restrict__ colidx, const float* __restrict__ dinv,
    const float* __restrict__ bias, uint* __restrict__ outT,
    float* __restrict__ Psum, float* __restrict__ Psq)
{
    int lane = threadIdx.x & 63, wid = threadIdx.x >> 6;
    int part = lane >> 5, fl = lane & 31;
    int gw = blockIdx.x * 4 + wid, nw = gridDim.x * 4;
    float bx = bias[2 * fl], by = bias[2 * fl + 1];
    float lsx = 0.f, lsy = 0.f, lqx = 0.f, lqy = 0.f;
    for (int i = gw; i < N_NODES; i += nw) {
        int iu = __builtin_amdgcn_readfirstlane(i);
        int s0 = rowptr[iu], e0 = rowptr[iu + 1];
        float ax = 0.f, ay = 0.f;
        if (!part) { uint w = zs[iu * 32 + fl]; ax = bflo(w); ay = bfhi(w); }
        int e = s0 + part;
        for (; e + 6 < e0; e += 8) {
            int j0 = colidx[e], j1 = colidx[e + 2], j2 = colidx[e + 4], j3 = colidx[e + 6];
            uint w0 = zs[j0 * 32 + fl], w1 = zs[j1 * 32 + fl];
            uint w2 = zs[j2 * 32 + fl], w3 = zs[j3 * 32 + fl];
            ax += bflo(w0); ay += bfhi(w0);
            ax += bflo(w1); ay += bfhi(w1);
            ax += bflo(w2); ay += bfhi(w2);
            ax += bflo(w3); ay += bfhi(w3);
        }
        for (; e < e0; e += 2) {
            uint w = zs[colidx[e] * 32 + fl];
            ax += bflo(w); ay += bfhi(w);
        }
        ax += __shfl_xor(ax, 32);
        ay += __shfl_xor(ay, 32);
        if (!part) {
            float di = dinv[iu];
            float tx_ = fmaxf(fmaf(di, ax, bx), 0.f);
            float ty_ = fmaxf(fmaf(di, ay, by), 0.f);
            outT[iu * 32 + fl] = pack2(tx_, ty_);
            lsx += tx_; lsy += ty_;
            lqx += tx_ * tx_; lqy += ty_ * ty_;
        }
    }
    __shared__ float ssum[64], ssq[64];
    if (threadIdx.x < 64) { ssum[threadIdx.x] = 0.f; ssq[threadIdx.x] = 0.f; }
    __syncthreads();
    if (!part) {
        atomicAdd(&ssum[2 * fl], lsx); atomicAdd(&ssum[2 * fl + 1], lsy);
        atomicAdd(&ssq[2 * fl], lqx);  atomicAdd(&ssq[2 * fl + 1], lqy);
    }
    __syncthreads();
    if (threadIdx.x < 64) {
        Psum[threadIdx.x * gridDim.x + blockIdx.x] = ssum[threadIdx.x];
        Psq[threadIdx.x * gridDim.x + blockIdx.x] = ssq[threadIdx.x];
    }
}

// agg_relu32: t = relu(Ahat(z)+b) -> f32 [N,32], stats partials
__global__ __launch_bounds__(256) void agg_relu32_kernel(
    const uint* __restrict__ zs, const int* __restrict__ rowptr,
    const int* __restrict__ colidx, const float* __restrict__ dinv,
    const float* __restrict__ bias, float2* __restrict__ outT,
    float* __restrict__ Psum, float* __restrict__ Psq)
{
    int lane = threadIdx.x & 63, wid = threadIdx.x >> 6;
    int part = lane >> 4, fl = lane & 15;
    int gw = blockIdx.x * 4 + wid, nw = gridDim.x * 4;
    float bx = bias[2 * fl], by = bias[2 * fl + 1];
    float lsx = 0.f, lsy = 0.f, lqx = 0.f, lqy = 0.f;
    for (int i = gw; i < N_NODES; i += nw) {
        int iu = __builtin_amdgcn_readfirstlane(i);
        int s0 = rowptr[iu], e0 = rowptr[iu + 1];
        float ax = 0.f, ay = 0.f;
        if (part == 0) { uint w = zs[iu * 16 + fl]; ax = bflo(w); ay = bfhi(w); }
        int e = s0 + part;
        for (; e + 12 < e0; e += 16) {
            int j0 = colidx[e], j1 = colidx[e + 4], j2 = colidx[e + 8], j3 = colidx[e + 12];
            uint w0 = zs[j0 * 16 + fl], w1 = zs[j1 * 16 + fl];
            uint w2 = zs[j2 * 16 + fl], w3 = zs[j3 * 16 + fl];
            ax += bflo(w0); ay += bfhi(w0);
            ax += bflo(w1); ay += bfhi(w1);
            ax += bflo(w2); ay += bfhi(w2);
            ax += bflo(w3); ay += bfhi(w3);
        }
        for (; e < e0; e += 4) {
            uint w = zs[colidx[e] * 16 + fl];
            ax += bflo(w); ay += bfhi(w);
        }
        ax += __shfl_xor(ax, 16); ax += __shfl_xor(ax, 32);
        ay += __shfl_xor(ay, 16); ay += __shfl_xor(ay, 32);
        if (lane < 16) {
            float di = dinv[iu];
            float tx_ = fmaxf(fmaf(di, ax, bx), 0.f);
            float ty_ = fmaxf(fmaf(di, ay, by), 0.f);
            outT[iu * 16 + fl] = make_float2(tx_, ty_);
            lsx += tx_; lsy += ty_;
            lqx += tx_ * tx_; lqy += ty_ * ty_;
        }
    }
    __shared__ float ssum[32], ssq[32];
    if (threadIdx.x < 32) { ssum[threadIdx.x] = 0.f; ssq[threadIdx.x] = 0.f; }
    __syncthreads();
    if (lane < 16) {
        atomicAdd(&ssum[2 * fl], lsx); atomicAdd(&ssum[2 * fl + 1], lsy);
        atomicAdd(&ssq[2 * fl], lqx);  atomicAdd(&ssq[2 * fl + 1], lqy);
    }
    __syncthreads();
    if (threadIdx.x < 32) {
        Psum[threadIdx.x * gridDim.x + blockIdx.x] = ssum[threadIdx.x];
        Psq[threadIdx.x * gridDim.x + blockIdx.x] = ssq[threadIdx.x];
    }
}

// ---------------- MFMA GEMM: out = f(A @ W + bias), A bf16 [N,K], W fragment-packed ----------------
// MODE 0: t=relu(acc+bias); stats; out bf16 = dinv[r]*t
// MODE 1: t=relu(acc+bias+rowsumP[r]*bias2); stats; out bf16 = t
// MODE 2: z=acc+bias; out bf16 = dinv[r]*z (no relu, no stats)
// Block: 256 thr = 4 waves, 16 rows/wave (64 rows/block), full DOUT per wave.
template <int K, int DOUT, int MODE>
__global__ __launch_bounds__(256) void mgemm_kernel(
    const ushort* __restrict__ A, const ushort* __restrict__ Wfrag,
    const float* __restrict__ bias, const float* __restrict__ bias2,
    const float* __restrict__ rowsumP, const float* __restrict__ dinv,
    ushort* __restrict__ outB, float* __restrict__ Psum, float* __restrict__ Psq)
{
    constexpr int KT = K / 32, CT = DOUT / 16;
    int tid = threadIdx.x;
    int lane = tid & 63, wid = tid >> 6;
    int r0 = blockIdx.x * 64 + wid * 16;
    int arow = r0 + (lane & 15);
    if (arow >= N_NODES) arow = N_NODES - 1;
    const ushort* aptr = A + (size_t)arow * K + (lane >> 4) * 8;

    f32x4 acc[CT];
#pragma unroll
    for (int ct = 0; ct < CT; ct++) acc[ct] = (f32x4){0.f, 0.f, 0.f, 0.f};

#pragma unroll
    for (int kt = 0; kt < KT; kt++) {
        bf16x8 af = *(const bf16x8*)(aptr + kt * 32);
        const ushort* wp = Wfrag + ((size_t)(kt * CT) * 64 + lane) * 8;
#pragma unroll
        for (int ct = 0; ct < CT; ct++) {
            bf16x8 bfr = *(const bf16x8*)(wp + (size_t)ct * 64 * 8);
            acc[ct] = __builtin_amdgcn_mfma_f32_16x16x32_bf16(af, bfr, acc[ct], 0, 0, 0);
        }
    }

    // epilogue: lane holds rows r0 + (lane>>4)*4 + i, col = ct*16 + (lane&15)
    int colbase = lane & 15;
    int rgrp = lane >> 4;
    int rows[4]; bool rok[4];
    float rP[4], rD[4];
#pragma unroll
    for (int i = 0; i < 4; i++) {
        int r = r0 + rgrp * 4 + i;
        rows[i] = r;
        rok[i] = (r < N_NODES);
        int rc = rok[i] ? r : 0;
        if constexpr (MODE == 1) rP[i] = rowsumP[rc];
        else rD[i] = dinv[rc];
    }

    __shared__ float ssum[DOUT], ssq[DOUT];
    if constexpr (MODE <= 1) {
        for (int c = tid; c < DOUT; c += 256) { ssum[c] = 0.f; ssq[c] = 0.f; }
        __syncthreads();
    }

#pragma unroll
    for (int ct = 0; ct < CT; ct++) {
        int col = ct * 16 + colbase;
        float b = bias[col];
        float b2 = 0.f;
        if constexpr (MODE == 1) b2 = bias2[col];
        float cs = 0.f, cq = 0.f;
#pragma unroll
        for (int i = 0; i < 4; i++) {
            float v = acc[ct][i] + b;
            if constexpr (MODE == 1) v = fmaf(rP[i], b2, v);
            if constexpr (MODE <= 1) v = fmaxf(v, 0.f);
            float w = (MODE == 1) ? v : rD[i] * v;
            if (rok[i]) {
                outB[(size_t)rows[i] * DOUT + col] = f2bf(w);
                if constexpr (MODE <= 1) { cs += v; cq += v * v; }
            }
        }
        if constexpr (MODE <= 1) {
            cs += __shfl_xor(cs, 16); cs += __shfl_xor(cs, 32);
            cq += __shfl_xor(cq, 16); cq += __shfl_xor(cq, 32);
            if (rgrp == 0) {
                atomicAdd(&ssum[col], cs);
                atomicAdd(&ssq[col], cq);
            }
        }
    }
    if constexpr (MODE <= 1) {
        __syncthreads();
        for (int c = tid; c < DOUT; c += 256) {
            Psum[(size_t)c * gridDim.x + blockIdx.x] = ssum[c];
            Psq[(size_t)c * gridDim.x + blockIdx.x] = ssq[c];
        }
    }
}

// ---------------- BN stat reduce -> scale/shift ----------------
__global__ __launch_bounds__(256) void reduce_bn_kernel(
    const float* __restrict__ Psum, const float* __restrict__ Psq, int nb,
    const float* __restrict__ g, const float* __restrict__ be,
    float* __restrict__ sOut, float* __restrict__ uOut)
{
    int c = blockIdx.x, t = threadIdx.x;
    float s = 0.f, q = 0.f;
    for (int i = t; i < nb; i += 256) {
        s += Psum[(size_t)c * nb + i];
        q += Psq[(size_t)c * nb + i];
    }
    __shared__ float rs[256], rq[256];
    rs[t] = s; rq[t] = q;
    __syncthreads();
    for (int off = 128; off > 0; off >>= 1) {
        if (t < off) { rs[t] += rs[t + off]; rq[t] += rq[t + off]; }
        __syncthreads();
    }
    if (t == 0) {
        float mu = rs[0] * (1.0f / N_NODES);
        float var = rq[0] * (1.0f / N_NODES) - mu * mu;
        float sv = g[c] * rsqrtf(var + BN_EPS);
        sOut[c] = sv;
        uOut[c] = be[c] - mu * sv;
    }
}

// ---------------- fold: Wf = s (row) * W ; v[c] = u @ W[:,c] ----------------
__global__ void foldW_kernel(const float* __restrict__ W, const float* __restrict__ s,
                             const float* __restrict__ u, float* __restrict__ Wf,
                             float* __restrict__ v, int din, int dout)
{
    int c = blockIdx.x, t = threadIdx.x;
    float contrib = 0.f;
    if (t < din) {
        float w = W[t * dout + c];
        Wf[t * dout + c] = s[t] * w;
        contrib = u[t] * w;
    }
    __shared__ float red[128];
    red[t] = contrib;
    __syncthreads();
    for (int off = 64; off > 0; off >>= 1) {
        if (t < off) red[t] += red[t + off];
        __syncthreads();
    }
    if (t == 0) v[c] = red[0];
}

// ---------------- final: h4 = s4*t4+u4, logits = h4@Wc+bc ----------------
__global__ __launch_bounds__(256) void final_kernel(
    const float* __restrict__ t4, const float* __restrict__ sArr,
    const float* __restrict__ uArr, const float* __restrict__ Wc,
    const float* __restrict__ bc, float* __restrict__ out_logits,
    float* __restrict__ out_h)
{
    __shared__ float sc[32], sh2[32], Wcs[160], bcs[5];
    int t = threadIdx.x;
    if (t < 32) { sc[t] = sArr[t]; sh2[t] = uArr[t]; }
    if (t < 160) Wcs[t] = Wc[t];
    if (t < 5) bcs[t] = bc[t];
    __syncthreads();
    int i = blockIdx.x * blockDim.x + t;
    if (i >= N_NODES) return;
    float hv[32];
#pragma unroll
    for (int f0 = 0; f0 < 32; f0 += 4) {
        float4 v = *(const float4*)&t4[(size_t)i * 32 + f0];
        hv[f0 + 0] = fmaf(sc[f0 + 0], v.x, sh2[f0 + 0]);
        hv[f0 + 1] = fmaf(sc[f0 + 1], v.y, sh2[f0 + 1]);
        hv[f0 + 2] = fmaf(sc[f0 + 2], v.z, sh2[f0 + 2]);
        hv[f0 + 3] = fmaf(sc[f0 + 3], v.w, sh2[f0 + 3]);
    }
#pragma unroll
    for (int f0 = 0; f0 < 32; f0 += 4) {
        float4 v = {hv[f0], hv[f0 + 1], hv[f0 + 2], hv[f0 + 3]};
        *(float4*)&out_h[(size_t)i * 32 + f0] = v;
    }
    float o[5];
#pragma unroll
    for (int c = 0; c < 5; c++) o[c] = bcs[c];
#pragma unroll
    for (int f = 0; f < 32; f++) {
        float hvf = hv[f];
#pragma unroll
        for (int c = 0; c < 5; c++) o[c] = fmaf(hvf, Wcs[f * 5 + c], o[c]);
    }
#pragma unroll
    for (int c = 0; c < 5; c++) out_logits[(size_t)i * 5 + c] = o[c];
}

extern "C" void kernel_launch(void* const* d_in, const int* in_sizes, int n_in,
                              void* d_out, int out_size, void* d_ws, size_t ws_size,
                              hipStream_t stream)
{
    const float* x = (const float*)d_in[0];
    const int* ei = (const int*)d_in[1];
    const float* W1 = (const float*)d_in[2];
    const float* b1 = (const float*)d_in[3];
    const float* g1 = (const float*)d_in[4];
    const float* be1 = (const float*)d_in[5];
    const float* W2 = (const float*)d_in[6];
    const float* b2 = (const float*)d_in[7];
    const float* g2 = (const float*)d_in[8];
    const float* be2 = (const float*)d_in[9];
    const float* W3 = (const float*)d_in[10];
    const float* b3 = (const float*)d_in[11];
    const float* g3 = (const float*)d_in[12];
    const float* be3 = (const float*)d_in[13];
    const float* W4 = (const float*)d_in[14];
    const float* b4 = (const float*)d_in[15];
    const float* g4 = (const float*)d_in[16];
    const float* be4 = (const float*)d_in[17];
    const float* Wc = (const float*)d_in[18];
    const float* bc = (const float*)d_in[19];

    char* ws = (char*)d_ws;
    size_t off = 0;
    auto alloc = [&](size_t bytes) -> void* {
        void* p = ws + off;
        off += (bytes + 255) & ~(size_t)255;
        return p;
    };
    uint* ch = (uint*)alloc(65536 * 4);
    uint* bucketBase = (uint*)alloc(257 * 4);
    int2* pair = (int2*)alloc((size_t)N_EDGES * 8);
    int* rowptr = (int*)alloc((size_t)(N_NODES + 1) * 4);
    float* dinv = (float*)alloc((size_t)N_NODES * 4);
    int* colidx = (int*)alloc((size_t)N_EDGES * 4);
    int* flag = (int*)alloc(256);
    float* rowsumP = (float*)alloc((size_t)N_NODES * 4);
    ushort* xs = (ushort*)alloc((size_t)N_NODES * 40 * 2);
    float* Wf = (float*)alloc(128 * 128 * 4);
    ushort* Wfrag = (ushort*)alloc(32768);
    float* vB = (float*)alloc(128 * 4);
    float* sArr = (float*)alloc(128 * 4);
    float* uArr = (float*)alloc(128 * 4);
    float* Psum = (float*)alloc((size_t)128 * 2048 * 4);
    float* Psq = (float*)alloc((size_t)128 * 2048 * 4);
    uint* bufA = (uint*)alloc((size_t)N_NODES * 64 * 4);  // t2 [N,128]bf16
    uint* bufB = (uint*)alloc((size_t)N_NODES * 32 * 4);  // a1 -> a2 -> z3s -> z4s
    uint* bufC = (uint*)alloc((size_t)N_NODES * 32 * 4);  // t1s -> t3
    float* bufF = (float*)alloc((size_t)N_NODES * 32 * 4); // t4 f32
    if (off > ws_size) return;

    // ---- CSR build (atomic-free) ----
    detect_kernel<<<1, 256, 0, stream>>>(ei, flag);
    coarseA_kernel<<<NB_C, 256, 0, stream>>>(ei, flag, ch);
    scanB_kernel<<<1, 256, 0, stream>>>(ch, bucketBase);
    scatterC_kernel<<<NB_C, 256, 0, stream>>>(ei, flag, ch, pair);
    bucketD_kernel<<<NB_D, 256, 0, stream>>>(pair, bucketBase, rowptr, dinv, colidx);

    // ---- prep ----
    xscale_kernel<<<(N_NODES * 40 + 255) / 256, 256, 0, stream>>>(x, dinv, xs);
    packW_kernel<<<16, 256, 0, stream>>>(W1, Wfrag, 39, 64, 64);

    // ---- Layer 1: a1 = Ahat x (bf16); t1 = relu(a1@W1+b1); stats1; t1s = bf16(dinv*t1) ----
    agg1_kernel<<<AGG_GRID, 256, 0, stream>>>((const uint*)xs, rowptr, colidx, dinv,
                                              bufB, rowsumP);
    mgemm_kernel<64, 64, 0><<<MG_GRID, 256, 0, stream>>>(
        (const ushort*)bufB, Wfrag, b1, nullptr, nullptr, dinv,
        (ushort*)bufC, Psum, Psq);
    reduce_bn_kernel<<<64, 256, 0, stream>>>(Psum, Psq, MG_GRID, g1, be1, sArr, uArr);
    foldW_kernel<<<128, 128, 0, stream>>>(W2, sArr, uArr, Wf, vB, 64, 128);
    packW_kernel<<<32, 256, 0, stream>>>(Wf, Wfrag, 64, 128, 64);

    // ---- Layer 2: a2 = Ahat t1s (bf16); t2 = relu(a2@W2f + b2 + rowsumP*v2); stats2 ----
    agg_only64_kernel<<<AGG_GRID, 256, 0, stream>>>(bufC, rowptr, colidx, dinv, bufB);
    mgemm_kernel<64, 128, 1><<<MG_GRID, 256, 0, stream>>>(
        (const ushort*)bufB, Wfrag, b2, vB, rowsumP, nullptr,
        (ushort*)bufA, Psum, Psq);
    reduce_bn_kernel<<<128, 256, 0, stream>>>(Psum, Psq, MG_GRID, g2, be2, sArr, uArr);
    foldW_kernel<<<64, 128, 0, stream>>>(W3, sArr, uArr, Wf, vB, 128, 64);
    packW_kernel<<<32, 256, 0, stream>>>(Wf, Wfrag, 128, 64, 128);

    // ---- Layer 3: z3s = bf16(dinv*(t2@W3f+v3)); t3 = relu(Ahat z3 + b3); stats3 ----
    mgemm_kernel<128, 64, 2><<<MG_GRID, 256, 0, stream>>>(
        (const ushort*)bufA, Wfrag, vB, nullptr, nullptr, dinv,
        (ushort*)bufB, nullptr, nullptr);
    agg_relu64_kernel<<<AGG_GRID, 256, 0, stream>>>(bufB, rowptr, colidx, dinv,
                                                    b3, bufC, Psum, Psq);
    reduce_bn_kernel<<<64, 256, 0, stream>>>(Psum, Psq, AGG_GRID, g3, be3, sArr, uArr);
    foldW_kernel<<<32, 128, 0, stream>>>(W4, sArr, uArr, Wf, vB, 64, 32);
    packW_kernel<<<16, 256, 0, stream>>>(Wf, Wfrag, 64, 32, 64);

    // ---- Layer 4: z4s = bf16(dinv*(t3@W4f+v4)); t4 = relu(Ahat z4 + b4); stats4 ----
    mgemm_kernel<64, 32, 2><<<MG_GRID, 256, 0, stream>>>(
        (const ushort*)bufC, Wfrag, vB, nullptr, nullptr, dinv,
        (ushort*)bufB, nullptr, nullptr);
    agg_relu32_kernel<<<AGG_GRID, 256, 0, stream>>>(bufB, rowptr, colidx, dinv,
                                                    b4, (float2*)bufF, Psum, Psq);
    reduce_bn_kernel<<<32, 256, 0, stream>>>(Psum, Psq, AGG_GRID, g4, be4, sArr, uArr);

    // ---- final ----
    float* out_logits = (float*)d_out;
    float* out_h = (float*)d_out + (size_t)N_NODES * 5;
    final_kernel<<<(N_NODES + 255) / 256, 256, 0, stream>>>(bufF, sArr, uArr, Wc, bc,
                                                            out_logits, out_h);
}